// Round 2
// baseline (726.543 us; speedup 1.0000x reference)
//
#include <hip/hip_runtime.h>

#define N_NODES 8192
#define N_EDGES 65536
#define LAT 128
#define GEN 944
#define ECOLS 816   // columns of env_ij_w actually used (0..816)
#define ENVN 48
#define LINN 768
#define MULT 16
#define SPH 9
#define XROW 144  // MULT*SPH

// ---- workspace layout (float offsets) ----
#define OFF_ENV   ((size_t)0)                            // N*816  env_node
#define OFF_KN    (OFF_ENV  + (size_t)N_NODES*ECOLS)     // N*256  Knode
#define OFF_XBUF  (OFF_KN   + (size_t)N_NODES*256)       // E*144  x
#define OFF_EX    (OFF_XBUF + (size_t)N_EDGES*XROW)      // E*16   scores->ex
#define OFF_DH    (OFF_EX   + (size_t)N_EDGES*MULT)      // N*128  delta_h   (zeroed)
#define OFF_DX    (OFF_DH   + (size_t)N_NODES*LAT)       // N*144  delta_X   (zeroed)
#define OFF_DEN   (OFF_DX   + (size_t)N_NODES*XROW)      // N*16   den       (zeroed)
#define OFF_NMAX  (OFF_DEN  + (size_t)N_NODES*MULT)      // N*16   max keys  (zeroed)

__device__ __forceinline__ unsigned fkey(float f) {
  unsigned u = __float_as_uint(f);
  return (u & 0x80000000u) ? ~u : (u | 0x80000000u);
}
__device__ __forceinline__ float fdecode(unsigned u) {
  u = (u & 0x80000000u) ? (u & 0x7fffffffu) : ~u;
  return __uint_as_float(u);
}

// ---------------- per-node precompute: env_node = silu(h@W1)@W2 (816 cols), Knode = h@W_key
__global__ __launch_bounds__(256) void k_node(
    const float* __restrict__ h, const float* __restrict__ W1,
    const float* __restrict__ W2, const float* __restrict__ Wk,
    float* __restrict__ env_node, float* __restrict__ Knode) {
  __shared__ float h_lds[8][LAT];
  __shared__ float s_lds[8][LAT];
  const int tid = threadIdx.x;
  const int nb = blockIdx.x * 8;

  { // stage 8 h rows
    int o = tid * 4, e = o >> 7, k = o & 127;
    *(float4*)&h_lds[e][k] = *(const float4*)&h[(size_t)(nb + e) * LAT + k];
  }
  __syncthreads();

  { // u = h@W1, silu -> s_lds   (thread: e=tid/32, 4 cols)
    int e = tid >> 5, c4 = (tid & 31) * 4;
    float a0 = 0, a1 = 0, a2 = 0, a3 = 0;
    for (int k0 = 0; k0 < LAT; k0 += 4) {
      float4 tv = *(float4*)&h_lds[e][k0];
      float4 w0 = *(const float4*)&W1[(k0 + 0) * LAT + c4];
      float4 w1 = *(const float4*)&W1[(k0 + 1) * LAT + c4];
      float4 w2 = *(const float4*)&W1[(k0 + 2) * LAT + c4];
      float4 w3 = *(const float4*)&W1[(k0 + 3) * LAT + c4];
      a0 += tv.x * w0.x + tv.y * w1.x + tv.z * w2.x + tv.w * w3.x;
      a1 += tv.x * w0.y + tv.y * w1.y + tv.z * w2.y + tv.w * w3.y;
      a2 += tv.x * w0.z + tv.y * w1.z + tv.z * w2.z + tv.w * w3.z;
      a3 += tv.x * w0.w + tv.y * w1.w + tv.z * w2.w + tv.w * w3.w;
    }
    s_lds[e][c4 + 0] = a0 / (1.f + expf(-a0));
    s_lds[e][c4 + 1] = a1 / (1.f + expf(-a1));
    s_lds[e][c4 + 2] = a2 / (1.f + expf(-a2));
    s_lds[e][c4 + 3] = a3 / (1.f + expf(-a3));
  }
  { // Knode = h@W_key (256 cols, 2 quads/thread)
    int e = tid >> 5;
#pragma unroll
    for (int t2 = 0; t2 < 2; ++t2) {
      int c4 = ((tid & 31) + 32 * t2) * 4;
      float a0 = 0, a1 = 0, a2 = 0, a3 = 0;
      for (int k0 = 0; k0 < LAT; k0 += 4) {
        float4 tv = *(float4*)&h_lds[e][k0];
        float4 w0 = *(const float4*)&Wk[(k0 + 0) * 256 + c4];
        float4 w1 = *(const float4*)&Wk[(k0 + 1) * 256 + c4];
        float4 w2 = *(const float4*)&Wk[(k0 + 2) * 256 + c4];
        float4 w3 = *(const float4*)&Wk[(k0 + 3) * 256 + c4];
        a0 += tv.x * w0.x + tv.y * w1.x + tv.z * w2.x + tv.w * w3.x;
        a1 += tv.x * w0.y + tv.y * w1.y + tv.z * w2.y + tv.w * w3.y;
        a2 += tv.x * w0.z + tv.y * w1.z + tv.z * w2.z + tv.w * w3.z;
        a3 += tv.x * w0.w + tv.y * w1.w + tv.z * w2.w + tv.w * w3.w;
      }
      float4 r = make_float4(a0, a1, a2, a3);
      *(float4*)&Knode[(size_t)(nb + e) * 256 + c4] = r;
    }
  }
  __syncthreads();

  // env_node = s@W2 (816 cols, 204 quads)
  if (tid < 204) {
    int c4 = tid * 4;
    float4 acc[8];
#pragma unroll
    for (int e = 0; e < 8; ++e) acc[e] = make_float4(0, 0, 0, 0);
    for (int k0 = 0; k0 < LAT; k0 += 4) {
      float4 w0 = *(const float4*)&W2[(size_t)(k0 + 0) * GEN + c4];
      float4 w1 = *(const float4*)&W2[(size_t)(k0 + 1) * GEN + c4];
      float4 w2 = *(const float4*)&W2[(size_t)(k0 + 2) * GEN + c4];
      float4 w3 = *(const float4*)&W2[(size_t)(k0 + 3) * GEN + c4];
#pragma unroll
      for (int e = 0; e < 8; ++e) {
        float4 tv = *(float4*)&s_lds[e][k0];
        acc[e].x += tv.x * w0.x + tv.y * w1.x + tv.z * w2.x + tv.w * w3.x;
        acc[e].y += tv.x * w0.y + tv.y * w1.y + tv.z * w2.y + tv.w * w3.y;
        acc[e].z += tv.x * w0.z + tv.y * w1.z + tv.z * w2.z + tv.w * w3.z;
        acc[e].w += tv.x * w0.w + tv.y * w1.w + tv.z * w2.w + tv.w * w3.w;
      }
    }
#pragma unroll
    for (int e = 0; e < 8; ++e)
      *(float4*)&env_node[(size_t)(nb + e) * ECOLS + c4] = acc[e];
  }
}

// ---------------- fused edge kernel: w = (t@W_rs)*env_j (cols 0..816) ;
//                  delta_h scatter (cols 0..128) ; x = env_weighter(w[0:48]) +
//                  eq_linear(w[48:816]) ; Q = t@Wq ; scores ; node max
__global__ __launch_bounds__(256) void k_edge(
    const float* __restrict__ t_ij, const float* __restrict__ X,
    const float* __restrict__ sph, const int* __restrict__ ectr,
    const int* __restrict__ enbr, const float* __restrict__ W_rs,
    const float* __restrict__ Wq, const float* __restrict__ env_node,
    const float* __restrict__ Knode, float* __restrict__ delta_h,
    float* __restrict__ x_buf, float* __restrict__ ex_buf,
    unsigned* __restrict__ nmax) {
  __shared__ float t_lds[8][LAT];
  __shared__ float sph_lds[8][12];
  __shared__ float Xj_lds[8][XROW];
  __shared__ float w_lds[8][ECOLS];   // cols 0..816 of env_ij_w
  __shared__ float q_lds[8][256];
  __shared__ int i_lds[8], j_lds[8];
  const int tid = threadIdx.x;
  const int eb = blockIdx.x * 8;

  if (tid < 8) { i_lds[tid] = ectr[eb + tid]; j_lds[tid] = enbr[eb + tid]; }
  { int o = tid * 4, e = o >> 7, k = o & 127;
    *(float4*)&t_lds[e][k] = *(const float4*)&t_ij[(size_t)(eb + e) * LAT + k]; }
  if (tid < 72) { int e = tid / 9, s = tid % 9; sph_lds[e][s] = sph[(size_t)(eb + e) * SPH + s]; }
  for (int o = tid; o < 8 * XROW; o += 256) {
    int e = o / XROW, r = o % XROW;
    Xj_lds[e][r] = X[(size_t)enbr[eb + e] * XROW + r];
  }
  __syncthreads();

  // 268 column-quads = 204 (W_rs cols 0..816) + 64 (W_query)
#pragma unroll
  for (int p = 0; p < 2; ++p) {
    int qid = p * 256 + tid;
    if (qid < 268) {
      const float* src; int ld, c4, modeA;
      if (qid < 204) { src = W_rs; ld = GEN; c4 = qid * 4; modeA = 1; }
      else           { src = Wq;   ld = 256; c4 = (qid - 204) * 4; modeA = 0; }
      float4 acc[8];
#pragma unroll
      for (int e = 0; e < 8; ++e) acc[e] = make_float4(0, 0, 0, 0);
      for (int k0 = 0; k0 < LAT; k0 += 4) {
        float4 w0 = *(const float4*)&src[(size_t)(k0 + 0) * ld + c4];
        float4 w1 = *(const float4*)&src[(size_t)(k0 + 1) * ld + c4];
        float4 w2 = *(const float4*)&src[(size_t)(k0 + 2) * ld + c4];
        float4 w3 = *(const float4*)&src[(size_t)(k0 + 3) * ld + c4];
#pragma unroll
        for (int e = 0; e < 8; ++e) {
          float4 tv = *(float4*)&t_lds[e][k0];
          acc[e].x += tv.x * w0.x + tv.y * w1.x + tv.z * w2.x + tv.w * w3.x;
          acc[e].y += tv.x * w0.y + tv.y * w1.y + tv.z * w2.y + tv.w * w3.y;
          acc[e].z += tv.x * w0.z + tv.y * w1.z + tv.z * w2.z + tv.w * w3.z;
          acc[e].w += tv.x * w0.w + tv.y * w1.w + tv.z * w2.w + tv.w * w3.w;
        }
      }
      if (modeA) {
#pragma unroll
        for (int e = 0; e < 8; ++e) {
          int j = j_lds[e];
          float4 ev = *(const float4*)&env_node[(size_t)j * ECOLS + c4];
          float v0 = acc[e].x * ev.x, v1 = acc[e].y * ev.y;
          float v2 = acc[e].z * ev.z, v3 = acc[e].w * ev.w;
          float4 r = make_float4(v0, v1, v2, v3);
          *(float4*)&w_lds[e][c4] = r;
          if (c4 < LAT) {
            float* dh = &delta_h[(size_t)i_lds[e] * LAT + c4];
            atomicAdd(dh + 0, v0); atomicAdd(dh + 1, v1);
            atomicAdd(dh + 2, v2); atomicAdd(dh + 3, v3);
          }
        }
      } else {
#pragma unroll
        for (int e = 0; e < 8; ++e) *(float4*)&q_lds[e][c4] = acc[e];
      }
    }
  }
  __syncthreads();

  // x = delta_spharm + delta_eq  (8*144 outputs)
  for (int o = tid; o < 8 * XROW; o += 256) {
    int e = o / XROW, r = o % XROW, m = r / SPH, s = r % SPH;
    int ir = (s == 0) ? 0 : ((s < 4) ? 1 : 2);
    float acc = sph_lds[e][s] * w_lds[e][ir * 16 + m];
    const float* lw = &w_lds[e][ENVN + ir * 256 + m * 16];
    const float* xj = &Xj_lds[e][s];
#pragma unroll
    for (int v = 0; v < 16; ++v) acc += 0.25f * lw[v] * xj[v * SPH];
    x_buf[(size_t)(eb + e) * XROW + r] = acc;
  }

  // scores[e][m] = 4 * sum_h Q[e][m][h]*Knode[j][m][h]
  if (tid < 128) {
    int e = tid >> 4, m = tid & 15;
    int j = j_lds[e];
    float acc = 0;
#pragma unroll
    for (int hh = 0; hh < 16; ++hh)
      acc += q_lds[e][m * 16 + hh] * Knode[(size_t)j * 256 + m * 16 + hh];
    float sc = 4.0f * acc;
    ex_buf[(size_t)(eb + e) * MULT + m] = sc;
    atomicMax(&nmax[i_lds[e] * MULT + m], fkey(sc));
  }
}

// ---------------- softmax pass 2: ex = exp(s - max), den scatter
__global__ __launch_bounds__(256) void k_den(
    const int* __restrict__ ectr, const unsigned* __restrict__ nmax,
    float* __restrict__ ex_buf, float* __restrict__ den) {
  int idx = blockIdx.x * 256 + threadIdx.x;
  int e = idx >> 4, m = idx & 15;
  int i = ectr[e];
  float mval = fdecode(nmax[i * MULT + m]);
  float ex = expf(ex_buf[idx] - mval);
  ex_buf[idx] = ex;
  atomicAdd(&den[i * MULT + m], ex);
}

// ---------------- delta_X scatter: delta_X[i] += x * alpha
__global__ __launch_bounds__(256) void k_dx(
    const int* __restrict__ ectr, const float* __restrict__ ex_buf,
    const float* __restrict__ den, const float* __restrict__ x_buf,
    float* __restrict__ delta_X) {
  size_t idx = (size_t)blockIdx.x * 256 + threadIdx.x;
  int e = (int)(idx / XROW), r = (int)(idx % XROW), m = r / SPH;
  int i = ectr[e];
  float alpha = ex_buf[(size_t)e * MULT + m] / (den[i * MULT + m] + 1e-20f);
  atomicAdd(&delta_X[(size_t)i * XROW + r], x_buf[idx] * alpha);
}

// ---------------- h_new = LayerNorm(h + delta_h)
__global__ __launch_bounds__(64) void k_hout(
    const float* __restrict__ h, const float* __restrict__ dh,
    const float* __restrict__ gamma, const float* __restrict__ beta,
    float* __restrict__ out) {
  int n = blockIdx.x, lane = threadIdx.x;
  size_t base = (size_t)n * LAT + lane * 2;
  float2 hv = *(const float2*)&h[base];
  float2 dv = *(const float2*)&dh[base];
  float v0 = hv.x + dv.x, v1 = hv.y + dv.y;
  float s = v0 + v1, ss = v0 * v0 + v1 * v1;
#pragma unroll
  for (int o = 32; o; o >>= 1) { s += __shfl_xor(s, o); ss += __shfl_xor(ss, o); }
  float mean = s * (1.f / 128.f);
  float var = ss * (1.f / 128.f) - mean * mean;
  float inv = rsqrtf(var + 1e-5f);
  int c = lane * 2;
  out[base + 0] = (v0 - mean) * inv * gamma[c + 0] + beta[c + 0];
  out[base + 1] = (v1 - mean) * inv * gamma[c + 1] + beta[c + 1];
}

// ---------------- X_new = SO3-LayerNorm(X + delta_X)
__global__ __launch_bounds__(192) void k_xout(
    const float* __restrict__ X, const float* __restrict__ dX,
    float* __restrict__ out) {
  __shared__ float ssq[3];
  int n = blockIdx.x, tid = threadIdx.x;
  if (tid < 3) ssq[tid] = 0.f;
  __syncthreads();
  float val = 0.f; int ir = 0;
  if (tid < XROW) {
    val = X[(size_t)n * XROW + tid] + dX[(size_t)n * XROW + tid];
    int s = tid % SPH;
    ir = (s == 0) ? 0 : ((s < 4) ? 1 : 2);
    atomicAdd(&ssq[ir], val * val);
  }
  __syncthreads();
  if (tid < XROW) {
    const float cnt[3] = {16.f, 48.f, 80.f};
    float rms = sqrtf(ssq[ir] / cnt[ir] + 1e-5f);
    out[(size_t)n * XROW + tid] = val / rms;
  }
}

extern "C" void kernel_launch(void* const* d_in, const int* in_sizes, int n_in,
                              void* d_out, int out_size, void* d_ws, size_t ws_size,
                              hipStream_t stream) {
  const float* h    = (const float*)d_in[0];
  const float* X    = (const float*)d_in[1];
  const float* t_ij = (const float*)d_in[2];
  const float* sph  = (const float*)d_in[3];
  const int*   ectr = (const int*)d_in[5];
  const int*   enbr = (const int*)d_in[6];
  const float* W_rs = (const float*)d_in[7];
  const float* W1   = (const float*)d_in[8];
  const float* W2   = (const float*)d_in[9];
  const float* gam  = (const float*)d_in[10];
  const float* bet  = (const float*)d_in[11];
  const float* Wq   = (const float*)d_in[12];
  const float* Wk   = (const float*)d_in[13];
  float* out = (float*)d_out;
  float* ws  = (float*)d_ws;

  float*    env_node = ws + OFF_ENV;
  float*    Knode    = ws + OFF_KN;
  float*    x_buf    = ws + OFF_XBUF;
  float*    ex_buf   = ws + OFF_EX;
  float*    delta_h  = ws + OFF_DH;
  float*    delta_X  = ws + OFF_DX;
  float*    den      = ws + OFF_DEN;
  unsigned* nmax     = (unsigned*)(ws + OFF_NMAX);

  // zero delta_h, delta_X, den, nmax (contiguous; key 0 == -inf sentinel)
  hipMemsetAsync(delta_h, 0,
                 (size_t)N_NODES * (LAT + XROW + MULT + MULT) * sizeof(float), stream);
  // t_ij passthrough output
  hipMemcpyAsync(out + (size_t)N_NODES * (LAT + XROW), d_in[2],
                 (size_t)N_EDGES * LAT * sizeof(float),
                 hipMemcpyDeviceToDevice, stream);

  k_node<<<N_NODES / 8, 256, 0, stream>>>(h, W1, W2, Wk, env_node, Knode);
  k_edge<<<N_EDGES / 8, 256, 0, stream>>>(t_ij, X, sph, ectr, enbr, W_rs, Wq,
                                          env_node, Knode, delta_h, x_buf, ex_buf, nmax);
  k_den<<<(N_EDGES * MULT) / 256, 256, 0, stream>>>(ectr, nmax, ex_buf, den);
  k_dx<<<((size_t)N_EDGES * XROW) / 256, 256, 0, stream>>>(ectr, ex_buf, den, x_buf, delta_X);
  k_hout<<<N_NODES, 64, 0, stream>>>(h, delta_h, gam, bet, out);
  k_xout<<<N_NODES, 192, 0, stream>>>(X, delta_X, out + (size_t)N_NODES * LAT);
}